// Round 4
// baseline (41.109 us; speedup 1.0000x reference)
//
#include <hip/hip_runtime.h>
#include <stdint.h>

// Problem constants (match reference)
#define BB 8
#define SS 4096
#define TOKEN_BITS 12
#define EMB 1024
#define NB 12
#define TABLE 4096
#define POS_BITS 13
#define SPB 16   // sequence positions per block in ram_embed

typedef float f32x4 __attribute__((ext_vector_type(4)));

// ---------------------------------------------------------------------------
// Kernel 1: build remapT[n][pat-bits] — pattern-packed remap.
// One block per neuron: stage the 16 KB table row in LDS (coalesced float4
// global reads — the ONLY pass over the 16 MB table), then loop over all
// 4096 patterns; lanes = 64 consecutive patterns, __ballot packs a uint64.
// remapT64[n*64 + pat/64], bit (pat & 63). 512 KB total.
// ---------------------------------------------------------------------------
__global__ __launch_bounds__(256) void build_remapT(const float* __restrict__ tables,
                                                    const int* __restrict__ conn,
                                                    uint64_t* __restrict__ remapT) {
    __shared__ float row[TABLE];
    __shared__ int csh[NB];
    const int n = blockIdx.x;
    const int t = threadIdx.x;
    if (t < NB) csh[t] = conn[n * NB + t];
    const f32x4* src = (const f32x4*)(tables + (size_t)n * TABLE);
    f32x4* dst = (f32x4*)row;
#pragma unroll
    for (int i = 0; i < 4; ++i)
        dst[t + 256 * i] = src[t + 256 * i];
    __syncthreads();
    int cr[NB];
#pragma unroll
    for (int j = 0; j < NB; ++j) cr[j] = csh[j];
    for (int base = 0; base < TABLE; base += 256) {
        int pat = base + t;
        int addr = 0;
#pragma unroll
        for (int j = 0; j < NB; ++j)
            addr = (addr << 1) | ((pat >> cr[j]) & 1);   // j=0 is MSB (reference order)
        uint64_t m = __ballot(row[addr] != 0.0f);
        if ((t & 63) == 0)
            remapT[(size_t)n * (TABLE / 64) + (pat >> 6)] = m;
    }
}

// ---------------------------------------------------------------------------
// Kernel 2: bit-transpose remapT -> remap[pat][neuron-bits].
// Output word remap32[pat*32 + w] has bit i = neuron 32w+i.
// Block covers one w and 256 consecutive patterns: the 32 loads per thread
// are wave-broadcast (lanes share 1-2 words), everything is L2-resident.
// ---------------------------------------------------------------------------
__global__ __launch_bounds__(256) void transpose_remap(const uint32_t* __restrict__ remapT32,
                                                       uint32_t* __restrict__ remap32) {
    const int w   = blockIdx.x >> 4;                       // 0..31
    const int pat = ((blockIdx.x & 15) << 8) | threadIdx.x;
    const int wordIdx = pat >> 5;
    const int bit     = pat & 31;
    uint32_t res = 0;
#pragma unroll
    for (int i = 0; i < 32; ++i) {
        int n = 32 * w + i;
        res |= ((remapT32[(size_t)n * (TABLE / 32) + wordIdx] >> bit) & 1u) << i;
    }
    remap32[(size_t)pat * (EMB / 32) + w] = res;
}

// ---------------------------------------------------------------------------
// Kernel 3: main embedding. One block per SPB=16 consecutive (b,s) rows.
// Threads 0..15 pack their row's 12-bit pattern straight from global (one
// barrier total). Then every thread issues ALL 16 remap-row loads up front
// (independent L2 reads — pure ILP, no load->store serialization), and emits
// one nontemporal f32x4 per row with integer-domain XOR of the pos bits.
// ---------------------------------------------------------------------------
__global__ __launch_bounds__(256) void ram_embed(const int* __restrict__ tokens,
                                                 const uint32_t* __restrict__ remap,
                                                 float* __restrict__ out) {
    const int g0 = blockIdx.x * SPB;            // first b*S+s row index
    const int t  = threadIdx.x;
    __shared__ int pats[SPB];
    if (t < SPB) {
        const int* tp = tokens + (size_t)(g0 + t) * TOKEN_BITS;
        int p = 0;
#pragma unroll
        for (int j = 0; j < TOKEN_BITS; ++j)
            p |= (tp[j] & 1) << j;
        pats[t] = p;
    }
    __syncthreads();

    const int w   = t >> 3;                     // which 32-bit word of the row
    const int sh4 = (t & 7) * 4;                // nibble position inside it

    uint32_t wv[SPB];
#pragma unroll
    for (int k = 0; k < SPB; ++k)
        wv[k] = remap[(size_t)pats[k] * (EMB / 32) + w];

    const int n0 = t * 4;
    int sh[4];
#pragma unroll
    for (int u = 0; u < 4; ++u)
        sh[u] = POS_BITS - 1 - ((n0 + u) % POS_BITS);
    const int sbase = g0 & (SS - 1);            // SPB divides SS, so b is fixed

#pragma unroll
    for (int k = 0; k < SPB; ++k) {
        const int s = sbase + k;
        uint32_t nib = (wv[k] >> sh4) & 0xFu;
        uint32_t pn  =  (uint32_t)((s >> sh[0]) & 1)
                     | ((uint32_t)((s >> sh[1]) & 1) << 1)
                     | ((uint32_t)((s >> sh[2]) & 1) << 2)
                     | ((uint32_t)((s >> sh[3]) & 1) << 3);
        uint32_t x = nib ^ pn;
        f32x4 o;
        o.x = (x & 1u) ? 1.0f : 0.0f;
        o.y = (x & 2u) ? 1.0f : 0.0f;
        o.z = (x & 4u) ? 1.0f : 0.0f;
        o.w = (x & 8u) ? 1.0f : 0.0f;
        __builtin_nontemporal_store(o, (f32x4*)(out + (size_t)(g0 + k) * EMB + n0));
    }
}

// ---------------------------------------------------------------------------
extern "C" void kernel_launch(void* const* d_in, const int* in_sizes, int n_in,
                              void* d_out, int out_size, void* d_ws, size_t ws_size,
                              hipStream_t stream) {
    const int*   tokens = (const int*)d_in[0];
    const float* tables = (const float*)d_in[1];
    const int*   conn   = (const int*)d_in[2];
    float*       out    = (float*)d_out;

    // ws layout: [0, 512KB) remapT (pattern-packed), [512KB, 1MB) remap (neuron-packed)
    uint64_t* remapT = (uint64_t*)d_ws;
    uint32_t* remap  = (uint32_t*)(remapT + EMB * (TABLE / 64));

    build_remapT<<<EMB, 256, 0, stream>>>(tables, conn, remapT);
    transpose_remap<<<(TABLE / 256) * (EMB / 32), 256, 0, stream>>>(
        (const uint32_t*)remapT, remap);
    ram_embed<<<BB * SS / SPB, 256, 0, stream>>>(tokens, remap, out);
}

// Round 5
// 39.314 us; speedup vs baseline: 1.0456x; 1.0456x over previous
//
#include <hip/hip_runtime.h>
#include <stdint.h>

// Problem constants (match reference)
#define BB 8
#define SS 4096
#define TOKEN_BITS 12
#define EMB 1024
#define NB 12
#define TABLE 4096
#define POS_BITS 13
#define SPB 8   // sequence positions per block in ram_embed

typedef float f32x4 __attribute__((ext_vector_type(4)));

// ---------------------------------------------------------------------------
// Kernel 1: build remapT[n][pat-bits] — pattern-packed remap.
// One block per neuron: stage the 16 KB table row in LDS (coalesced float4
// global reads — the ONLY pass over the 16 MB table), then loop over all
// 4096 patterns; lanes = 64 consecutive patterns, __ballot packs a uint64.
// remapT64[n*64 + pat/64], bit (pat & 63). 512 KB total.
// ---------------------------------------------------------------------------
__global__ __launch_bounds__(256) void build_remapT(const float* __restrict__ tables,
                                                    const int* __restrict__ conn,
                                                    uint64_t* __restrict__ remapT) {
    __shared__ float row[TABLE];
    __shared__ int csh[NB];
    const int n = blockIdx.x;
    const int t = threadIdx.x;
    if (t < NB) csh[t] = conn[n * NB + t];
    const f32x4* src = (const f32x4*)(tables + (size_t)n * TABLE);
    f32x4* dst = (f32x4*)row;
#pragma unroll
    for (int i = 0; i < 4; ++i)
        dst[t + 256 * i] = src[t + 256 * i];
    __syncthreads();
    int cr[NB];
#pragma unroll
    for (int j = 0; j < NB; ++j) cr[j] = csh[j];
    for (int base = 0; base < TABLE; base += 256) {
        int pat = base + t;
        int addr = 0;
#pragma unroll
        for (int j = 0; j < NB; ++j)
            addr = (addr << 1) | ((pat >> cr[j]) & 1);   // j=0 is MSB (reference order)
        uint64_t m = __ballot(row[addr] != 0.0f);
        if ((t & 63) == 0)
            remapT[(size_t)n * (TABLE / 64) + (pat >> 6)] = m;
    }
}

// ---------------------------------------------------------------------------
// Kernel 2: bit-transpose remapT -> remap[pat][neuron-bits].
// Output word remap32[pat*32 + w] has bit i = neuron 32w+i.
// Block covers one w and 256 consecutive patterns: the 32 loads per thread
// are wave-broadcast (lanes share 1-2 words), everything is L2-resident.
// ---------------------------------------------------------------------------
__global__ __launch_bounds__(256) void transpose_remap(const uint32_t* __restrict__ remapT32,
                                                       uint32_t* __restrict__ remap32) {
    const int w   = blockIdx.x >> 4;                       // 0..31
    const int pat = ((blockIdx.x & 15) << 8) | threadIdx.x;
    const int wordIdx = pat >> 5;
    const int bit     = pat & 31;
    uint32_t res = 0;
#pragma unroll
    for (int i = 0; i < 32; ++i) {
        int n = 32 * w + i;
        res |= ((remapT32[(size_t)n * (TABLE / 32) + wordIdx] >> bit) & 1u) << i;
    }
    remap32[(size_t)pat * (EMB / 32) + w] = res;
}

// ---------------------------------------------------------------------------
// Kernel 3: main embedding. One block per SPB=8 consecutive (b,s) rows.
// Identical to the R3 kernel EXCEPT the store: plain (cached, write-back)
// f32x4 store instead of __builtin_nontemporal_store. A/B test of the NT
// flag's effect on HBM write efficiency.
// ---------------------------------------------------------------------------
__global__ __launch_bounds__(256) void ram_embed(const int* __restrict__ tokens,
                                                 const uint32_t* __restrict__ remap,
                                                 float* __restrict__ out) {
    const int g0 = blockIdx.x * SPB;            // first b*S+s row index
    const int t  = threadIdx.x;
    __shared__ int tok[SPB * TOKEN_BITS];
    __shared__ int pats[SPB];
    if (t < SPB * TOKEN_BITS)
        tok[t] = tokens[(size_t)g0 * TOKEN_BITS + t];
    __syncthreads();
    if (t < SPB) {
        int p = 0;
#pragma unroll
        for (int j = 0; j < TOKEN_BITS; ++j)
            p |= (tok[t * TOKEN_BITS + j] & 1) << j;
        pats[t] = p;
    }
    __syncthreads();

    const int n0 = t * 4;
    int sh[4];
#pragma unroll
    for (int u = 0; u < 4; ++u)
        sh[u] = POS_BITS - 1 - ((n0 + u) % POS_BITS);
    const int sbase = g0 & (SS - 1);            // SPB divides SS, so b is fixed

    for (int k = 0; k < SPB; ++k) {
        const int pat = pats[k];
        const int s   = sbase + k;
        uint32_t word = remap[(size_t)pat * (EMB / 32) + (t >> 3)];
        uint32_t nib  = (word >> ((t & 7) * 4)) & 0xFu;
        uint32_t pn   =  (uint32_t)((s >> sh[0]) & 1)
                      | ((uint32_t)((s >> sh[1]) & 1) << 1)
                      | ((uint32_t)((s >> sh[2]) & 1) << 2)
                      | ((uint32_t)((s >> sh[3]) & 1) << 3);
        uint32_t x = nib ^ pn;
        f32x4 o;
        o.x = (x & 1u) ? 1.0f : 0.0f;
        o.y = (x & 2u) ? 1.0f : 0.0f;
        o.z = (x & 4u) ? 1.0f : 0.0f;
        o.w = (x & 8u) ? 1.0f : 0.0f;
        *(f32x4*)(out + (size_t)(g0 + k) * EMB + n0) = o;   // plain store (A/B vs NT)
    }
}

// ---------------------------------------------------------------------------
extern "C" void kernel_launch(void* const* d_in, const int* in_sizes, int n_in,
                              void* d_out, int out_size, void* d_ws, size_t ws_size,
                              hipStream_t stream) {
    const int*   tokens = (const int*)d_in[0];
    const float* tables = (const float*)d_in[1];
    const int*   conn   = (const int*)d_in[2];
    float*       out    = (float*)d_out;

    // ws layout: [0, 512KB) remapT (pattern-packed), [512KB, 1MB) remap (neuron-packed)
    uint64_t* remapT = (uint64_t*)d_ws;
    uint32_t* remap  = (uint32_t*)(remapT + EMB * (TABLE / 64));

    build_remapT<<<EMB, 256, 0, stream>>>(tables, conn, remapT);
    transpose_remap<<<(TABLE / 256) * (EMB / 32), 256, 0, stream>>>(
        (const uint32_t*)remapT, remap);
    ram_embed<<<BB * SS / SPB, 256, 0, stream>>>(tokens, remap, out);
}